// Round 19
// baseline (260.946 us; speedup 1.0000x reference)
//
#include <hip/hip_runtime.h>
#include <hip/hip_bf16.h>

#define Bn 64
#define Kn 24
#define Nn 934
#define NBLK 4
#define GCH 234          // points per gram block
#define NPTS 16
#define RNDS 15          // 15*16 = 240 >= 234
#define GPK 12090        // 155*156/2 packed lower (row 154 = rhs row)
#define PB 11
#define NPAN 14
#define ST 512
#define STR 168          // LDS row stride in floats
#define GT 1024          // k_gram threads (16 waves)
#define MAXT 4           // max tiles per wave

#define G_BYTES ((size_t)Bn * GPK * 8)

typedef __attribute__((ext_vector_type(4))) double f64x4;

__device__ __forceinline__ int rb(int i) { return (i * (i + 1)) >> 1; }

// ---------------- k_pre: stream-reduce b_s_ and xm over K -------------------
__global__ __launch_bounds__(1024) void k_pre(
    const float* __restrict__ uv, const float* __restrict__ xm,
    const float* __restrict__ bs, const float* __restrict__ Wp,
    const float* __restrict__ m00, const float* __restrict__ m11,
    const float* __restrict__ m02, const float* __restrict__ m12,
    float* __restrict__ pre)
{
    __shared__ float smL[32][30];
    __shared__ float xsL[32][3];
    const int tid = threadIdx.x;
    const int b = blockIdx.y;
    const int n0 = blockIdx.x * 32;
    const float f0 = m00[b], f1 = m11[b], cx = m02[b], cy = m12[b];

    if (tid < 960) {
        const int ni = tid / 30, c = tid - ni * 30;
        const int nc = min(n0 + ni, Nn - 1);
        float acc = 0.0f;
        const float* bp = bs + ((size_t)(b * Kn) * Nn + nc) * 30 + c;
        #pragma unroll
        for (int k = 0; k < Kn; ++k) acc += bp[(size_t)k * Nn * 30];
        smL[ni][c] = acc;
    } else {
        const int v = tid - 960;
        #pragma unroll
        for (int rep = 0; rep < 2; ++rep) {
            const int w = v + rep * 64;
            if (w < 96) {
                const int ni = w / 3, c = w - ni * 3;
                const int nc = min(n0 + ni, Nn - 1);
                float acc = 0.0f;
                const float* xp = xm + ((size_t)(b * Kn) * Nn + nc) * 3 + c;
                #pragma unroll
                for (int k = 0; k < Kn; ++k) acc += xp[(size_t)k * Nn * 3];
                xsL[ni][c] = acc;
            }
        }
    }
    __syncthreads();

    if (tid < 704) {
        const int ni = tid / 22, e = tid - ni * 22;
        const int n = n0 + ni;
        if (n < Nn) {
            const float u = uv[((size_t)b * Nn + n) * 2 + 0];
            const float v = uv[((size_t)b * Nn + n) * 2 + 1];
            const float w = Wp[(size_t)b * Nn + n];
            const float dxu = cx - u, dyv = cy - v;
            float val;
            if (e < 10)       val = w * (f0 * smL[ni][e] + dxu * smL[ni][20 + e]);
            else if (e < 20)  val = w * (f1 * smL[ni][e] + dyv * smL[ni][e + 10]);
            else if (e == 20) val = w * (-f0 * xsL[ni][0] - dxu * xsL[ni][2]);
            else              val = w * (-f1 * xsL[ni][1] - dyv * xsL[ni][2]);
            pre[((size_t)b * Nn + n) * 22 + e] = val;
        }
    }
}

// ------- k_gram: fp64 MFMA Gram, 16 waves (4/SIMD), probed layout -----------
__global__ __launch_bounds__(GT, 1) void k_gram(
    const float* __restrict__ uv, const float* __restrict__ xm,
    const float* __restrict__ blend, const float* __restrict__ Wp,
    const float* __restrict__ m00, const float* __restrict__ m11,
    const float* __restrict__ m02, const float* __restrict__ m12,
    const float* __restrict__ pre, double* __restrict__ Gpk)
{
    __shared__ float rowsF[2][2 * NPTS][STR];
    const int tid = threadIdx.x;
    const int b = blockIdx.y;
    const int n0 = blockIdx.x * GCH;
    const int nEnd = min(n0 + GCH, Nn);
    const float f0 = m00[b], f1 = m11[b], cx = m02[b], cy = m12[b];

    const int pt = (tid >> 4) & 15, s = tid & 15;   // builders: tid<256
    const int wave = tid >> 6, lane = tid & 63;

    // ---- probe the f64 MFMA fragment layouts empirically ----
    const f64x4 zz = {0.0, 0.0, 0.0, 0.0};
    const f64x4 pr = __builtin_amdgcn_mfma_f64_16x16x4f64((double)lane, 1.0, zz, 0, 0, 0);
    const f64x4 pc = __builtin_amdgcn_mfma_f64_16x16x4f64(1.0, (double)lane, zz, 0, 0, 0);
    const int v0 = (int)pr[0];
    const bool ac0 = (v0 >= 96) && (v0 <= 156) && (((v0 - 96) & 3) == 0);
    const int arow = ac0 ? (lane & 15) : (lane >> 2);
    const int ak   = ac0 ? (lane >> 4) : (lane & 3);
    const int w0 = (int)pc[0];
    const bool bc0 = (w0 >= 96) && (w0 <= 156) && (((w0 - 96) & 3) == 0);
    const int bcol = bc0 ? (lane & 15) : (lane >> 2);
    const int bk   = bc0 ? (lane >> 4) : (lane & 3);
    int orow[4], ocol[4];
    #pragma unroll
    for (int r2 = 0; r2 < 4; ++r2) {
        const int vr = (int)pr[r2];
        orow[r2] = ac0 ? ((vr - 96) >> 2) : ((vr - 6) >> 4);
        const int wr = (int)pc[r2];
        ocol[r2] = bc0 ? ((wr - 96) >> 2) : ((wr - 6) >> 4);
    }

    // tile lists: builder waves (0-3) 2 tiles, waves 4-15 get 4 (guard <55)
    const int t0 = (wave < 4) ? wave * 2 : 8 + (wave - 4) * 4;
    const int cnt = (wave < 4) ? 2 : 4;
    int Ia[MAXT], Ja[MAXT];
    {
        int Iv = 0, Jv = t0;
        while (Jv > Iv) { Jv -= (Iv + 1); ++Iv; }
        #pragma unroll
        for (int t = 0; t < MAXT; ++t) {
            Ia[t] = Iv; Ja[t] = Jv;
            ++Jv;
            if (Jv > Iv) { Jv = 0; ++Iv; }
        }
    }

    f64x4 acc[MAXT];
    #pragma unroll
    for (int t = 0; t < MAXT; ++t) acc[t] = (f64x4){0.0, 0.0, 0.0, 0.0};

    float pf[11];
    const bool isBd = tid < 256;

    auto PF = [&](int rnd) {
        if (!isBd) return;
        const int nc = min(n0 + rnd * NPTS + pt, Nn - 1);
        if (s < 12) {
            const int k0 = 2 * s;
            const float* xa = xm + ((size_t)(b * Kn + k0) * Nn + nc) * 3;
            const float* xb = xm + ((size_t)(b * Kn + k0 + 1) * Nn + nc) * 3;
            pf[0] = xa[0]; pf[1] = xa[1]; pf[2] = xa[2];
            pf[3] = xb[0]; pf[4] = xb[1]; pf[5] = xb[2];
            pf[6] = blend[nc * Kn + k0];
            pf[7] = blend[nc * Kn + k0 + 1];
            pf[8] = uv[((size_t)b * Nn + nc) * 2 + 0];
            pf[9] = uv[((size_t)b * Nn + nc) * 2 + 1];
            pf[10] = Wp[(size_t)b * Nn + nc];
        } else if (s < 15) {
            const int e0 = (s - 12) * 8;
            const float* pp = pre + ((size_t)b * Nn + nc) * 22;
            #pragma unroll
            for (int j = 0; j < 8; ++j) pf[j] = (e0 + j < 22) ? pp[e0 + j] : 0.0f;
        }
    };
    auto WR = [&](int rnd, int bufi) {
        if (!isBd) return;
        const int n = n0 + rnd * NPTS + pt;
        float* rx = &rowsF[bufi][2 * pt][0];
        float* ry = &rowsF[bufi][2 * pt + 1][0];
        if (s < 12) {
            #pragma unroll
            for (int jj = 0; jj < 2; ++jj) {
                float vx[6], vy[6];
                if (n < nEnd) {
                    const float x0 = pf[jj * 3 + 0], x1 = pf[jj * 3 + 1], x2 = pf[jj * 3 + 2];
                    const float dxu = cx - pf[8], dyv = cy - pf[9], w = pf[10];
                    const float wbl = w * pf[6 + jj];
                    vx[0] = w * dxu * x1; vx[1] = w * (f0 * x2 - dxu * x0); vx[2] = -w * f0 * x1;
                    vx[3] = wbl * f0;     vx[4] = 0.0f;                     vx[5] = wbl * dxu;
                    vy[0] = w * (dyv * x1 - f1 * x2); vy[1] = -w * dyv * x0; vy[2] = w * f1 * x0;
                    vy[3] = 0.0f;         vy[4] = wbl * f1;                 vy[5] = wbl * dyv;
                } else {
                    #pragma unroll
                    for (int e = 0; e < 6; ++e) { vx[e] = 0.0f; vy[e] = 0.0f; }
                }
                const int cb = 6 * (2 * s + jj);
                #pragma unroll
                for (int e = 0; e < 6; ++e) {
                    rx[cb + e] = vx[e];
                    ry[cb + e] = vy[e];
                }
            }
        } else if (s < 15) {
            const int e0 = (s - 12) * 8;
            #pragma unroll
            for (int j = 0; j < 8; ++j) {
                const int e = e0 + j;
                if (e < 22) {
                    const float val = (n < nEnd) ? pf[j] : 0.0f;
                    if (e < 10)       rx[144 + e] = val;
                    else if (e < 20)  ry[144 + (e - 10)] = val;
                    else if (e == 20) rx[154] = val;
                    else              ry[154] = val;
                }
            }
        }
    };

    // zero pad cols 155..159
    for (int idx = tid; idx < 320; idx += GT) {
        const int bufi = idx / 160, rem = idx % 160;
        rowsF[bufi][rem / 5][155 + rem % 5] = 0.0f;
    }

    PF(0);
    WR(0, 0);
    PF(1);
    __syncthreads();

    for (int r = 0; r < RNDS; ++r) {
        const int cur = r & 1;
        if (r < RNDS - 1) {
            WR(r + 1, cur ^ 1);
            if (r + 2 < RNDS) PF(r + 2);
        }
        #pragma unroll
        for (int ksl = 0; ksl < 8; ++ksl) {
            const float* rowA = &rowsF[cur][4 * ksl + ak][0];
            const float* rowB = &rowsF[cur][4 * ksl + bk][0];
            #pragma unroll
            for (int t = 0; t < MAXT; ++t) {
                if (t < cnt && t0 + t < 55) {
                    const double av = (double)rowA[16 * Ia[t] + arow];
                    const double bv = (double)rowB[16 * Ja[t] + bcol];
                    acc[t] = __builtin_amdgcn_mfma_f64_16x16x4f64(av, bv, acc[t], 0, 0, 0);
                }
            }
        }
        __syncthreads();
    }

    // write-out via probed output mapping
    double* Gb = Gpk + (size_t)b * GPK;
    #pragma unroll
    for (int t = 0; t < MAXT; ++t) {
        if (t < cnt && t0 + t < 55) {
            #pragma unroll
            for (int rr = 0; rr < 4; ++rr) {
                const int gi = 16 * Ia[t] + orow[rr];
                const int gj = 16 * Ja[t] + ocol[rr];
                if (gi < 155 && gj < 155 && gj <= gi)
                    unsafeAtomicAdd(&Gb[rb(gi) + gj], acc[t][rr]);
            }
        }
    }
}

// ------- k_solve: bordered LDL^T, 256-VGPR budget (no dblk spill) -----------
__global__ __launch_bounds__(ST, 2) void k_solve(
    const float* __restrict__ pbeta, const float* __restrict__ vR,
    const double* __restrict__ Gpk, float* __restrict__ out)
{
    __shared__ double tri[12090];     // packed lower 155 rows (row 154 = rhs)
    __shared__ double fd[NPAN][66];   // factored diag blocks
    __shared__ double Pp[144][PB];    // scaled panel rows
    __shared__ double Qq[144][PB];    // raw panel rows
    __shared__ double cv[160];        // final solution x (written in bwd)
    __shared__ double xv[160];        // w = D^-1 L^-1 c, then bwd-updated
    __shared__ double dinv[160];
    const int tid = threadIdx.x;
    const int b = blockIdx.x;
    const double lam2 = 1.0 / 9.0;
    const double* Gb = Gpk + (size_t)b * GPK;

    for (int idx = tid; idx < GPK; idx += ST) tri[idx] = Gb[idx];
    __syncthreads();
    if (tid < 10) {
        const int d = 144 + tid;
        tri[rb(d) + d] += lam2;                                  // Tikhonov
        tri[rb(154) + 144 + tid] += lam2 * (double)pbeta[b * 10 + tid];  // rhs reg
    }
    __syncthreads();

    // ===== bordered factorization: panels over cols 0..153, rows 0..154 =====
    for (int p = 0; p < NPAN; ++p) {
        const int c0 = p * PB, r0 = c0 + PB;
        const int m2 = 155 - r0;   // trailing rows incl. rhs row

        // phase 1: diag block factor, redundant in registers
        double dblk[66], dl[PB];
        #pragma unroll
        for (int r = 0; r < PB; ++r) {
            const int baser = rb(c0 + r) + c0;
            #pragma unroll
            for (int c = 0; c <= r; ++c) dblk[r * (r + 1) / 2 + c] = tri[baser + c];
        }
        #pragma unroll
        for (int j = 0; j < PB; ++j) {
            const double invd = 1.0 / dblk[j * (j + 1) / 2 + j];
            dl[j] = invd;
            #pragma unroll
            for (int r = j + 1; r < PB; ++r) {
                const double mr = dblk[r * (r + 1) / 2 + j] * invd;
                #pragma unroll
                for (int c = j + 1; c <= r; ++c)
                    dblk[r * (r + 1) / 2 + c] -= mr * dblk[c * (c + 1) / 2 + j];
            }
        }
        if (tid == 0) {
            #pragma unroll
            for (int e = 0; e < 66; ++e) fd[p][e] = dblk[e];
            #pragma unroll
            for (int j = 0; j < PB; ++j) dinv[c0 + j] = dl[j];
        }

        // phase 2: panel rows (incl. row 154 = rhs -> fwd substitution free)
        for (int i = r0 + tid; i < 155; i += ST) {
            const int ip = i - r0;
            const int base = rb(i) + c0;
            double a[PB], bbv[PB];
            #pragma unroll
            for (int k = 0; k < PB; ++k) a[k] = tri[base + k];
            #pragma unroll
            for (int t = 0; t < PB; ++t) {
                const double bt = a[t] * dl[t];
                bbv[t] = bt;
                #pragma unroll
                for (int k = t + 1; k < PB; ++k)
                    a[k] -= bt * dblk[k * (k + 1) / 2 + t];
            }
            #pragma unroll
            for (int k = 0; k < PB; ++k) {
                tri[base + k] = a[k]; Pp[ip][k] = bbv[k]; Qq[ip][k] = a[k];
            }
        }
        __syncthreads();

        // phase 3: trailing rank-11 update, flat ST-strided (512-wide)
        {
            const int tot = (m2 * (m2 + 1)) >> 1;
            for (int e = tid; e < tot; e += ST) {
                int row = (int)((sqrtf(8.0f * (float)e + 1.0f) - 1.0f) * 0.5f);
                while ((row + 1) * (row + 2) / 2 <= e) ++row;
                while (row * (row + 1) / 2 > e) --row;
                const int col = e - ((row * (row + 1)) >> 1);
                double sum = 0.0;
                #pragma unroll
                for (int k = 0; k < PB; ++k) sum += Pp[row][k] * Qq[col][k];
                tri[rb(r0 + row) + r0 + col] -= sum;
            }
        }
        __syncthreads();
    }

    // w = D^-1 L^-1 c directly from factored rhs row
    for (int j = tid; j < 154; j += ST) xv[j] = tri[rb(154) + j] * dinv[j];
    __syncthreads();

    // ================= backward substitution =================
    for (int p = NPAN - 1; p >= 0; --p) {
        const int c0 = p * PB;
        double x[PB], dl[PB];
        #pragma unroll
        for (int r = 0; r < PB; ++r) { dl[r] = dinv[c0 + r]; x[r] = xv[c0 + r]; }
        #pragma unroll
        for (int j = PB - 1; j >= 1; --j) {
            #pragma unroll
            for (int i2 = 0; i2 < j; ++i2)
                x[i2] -= dl[i2] * fd[p][j * (j + 1) / 2 + i2] * x[j];
        }
        if (tid == 0) {
            #pragma unroll
            for (int r = 0; r < PB; ++r) cv[c0 + r] = x[r];
        }
        for (int i = tid; i < c0; i += ST) {
            double sum = 0.0;
            #pragma unroll
            for (int jj = 0; jj < PB; ++jj) sum += tri[rb(c0 + jj) + i] * x[jj];
            xv[i] -= dinv[i] * sum;
        }
        __syncthreads();
    }

    // ================= epilogue: Rodrigues + outputs (float32) ==========
    if (tid < Kn) {
        const int k = tid;
        const double rxv = cv[6 * k + 0], ryv = cv[6 * k + 1], rzv = cv[6 * k + 2];
        const double t0 = cv[6 * k + 3], t1 = cv[6 * k + 4], t2 = cv[6 * k + 5];
        const double nrm = sqrt(rxv * rxv + ryv * ryv + rzv * rzv);
        const double th = fmax(nrm, 1e-8);
        const double ax = rxv / th, ay = ryv / th, az = rzv / th;
        const double c = cos(th), sn = sin(th), mc = 1.0 - c;
        double R[3][3];
        R[0][0] = c + mc * ax * ax;        R[0][1] = -sn * az + mc * ax * ay; R[0][2] =  sn * ay + mc * ax * az;
        R[1][0] =  sn * az + mc * ay * ax; R[1][1] = c + mc * ay * ay;        R[1][2] = -sn * ax + mc * ay * az;
        R[2][0] = -sn * ay + mc * az * ax; R[2][1] =  sn * ax + mc * az * ay; R[2][2] = c + mc * az * az;

        const float* VRp = vR + ((size_t)(b * Kn + k)) * 16;
        float* oc = out + ((size_t)(b * Kn + k)) * 16;
        #pragma unroll
        for (int r = 0; r < 3; ++r)
            #pragma unroll
            for (int cc = 0; cc < 4; ++cc) {
                const double val = R[r][0] * (double)VRp[0 * 4 + cc]
                                 + R[r][1] * (double)VRp[1 * 4 + cc]
                                 + R[r][2] * (double)VRp[2 * 4 + cc];
                oc[r * 4 + cc] = (float)val;
            }
        #pragma unroll
        for (int cc = 0; cc < 4; ++cc) oc[12 + cc] = VRp[12 + cc];

        float* ot = out + 24576 + ((size_t)(b * Kn + k)) * 3;
        ot[0] = (float)t0; ot[1] = (float)t1; ot[2] = (float)t2;

        float* orp = out + 29824 + ((size_t)(b * Kn + k)) * 9;
        #pragma unroll
        for (int r = 0; r < 3; ++r)
            #pragma unroll
            for (int cc = 0; cc < 3; ++cc)
                orp[r * 3 + cc] = (float)R[r][cc];
    }
    if (tid >= 32 && tid < 42) {
        out[29184 + b * 10 + (tid - 32)] = (float)cv[144 + (tid - 32)];
    }
}

extern "C" void kernel_launch(void* const* d_in, const int* in_sizes, int n_in,
                              void* d_out, int out_size, void* d_ws, size_t ws_size,
                              hipStream_t stream) {
    const float* uv    = (const float*)d_in[0];
    const float* xm    = (const float*)d_in[1];
    const float* bs    = (const float*)d_in[2];
    const float* blend = (const float*)d_in[3];
    const float* Wp    = (const float*)d_in[4];
    const float* m00   = (const float*)d_in[5];
    const float* m11   = (const float*)d_in[6];
    const float* m02   = (const float*)d_in[7];
    const float* m12   = (const float*)d_in[8];
    const float* pbeta = (const float*)d_in[9];
    const float* vRp   = (const float*)d_in[10];
    float* out = (float*)d_out;
    double* Gpk = (double*)d_ws;
    float* pre = (float*)((char*)d_ws + G_BYTES);

    hipMemsetAsync(d_ws, 0, G_BYTES, stream);

    dim3 gP((Nn + 31) / 32, Bn);
    k_pre<<<gP, 1024, 0, stream>>>(uv, xm, bs, Wp, m00, m11, m02, m12, pre);

    dim3 gG(NBLK, Bn);
    k_gram<<<gG, GT, 0, stream>>>(uv, xm, blend, Wp, m00, m11, m02, m12, pre, Gpk);

    k_solve<<<Bn, ST, 0, stream>>>(pbeta, vRp, Gpk, out);
}

// Round 20
// 229.208 us; speedup vs baseline: 1.1385x; 1.1385x over previous
//
#include <hip/hip_runtime.h>
#include <hip/hip_bf16.h>

#define Bn 64
#define Kn 24
#define Nn 934
#define NBLK 4
#define GCH 234          // points per gram block
#define NPTS 16
#define RNDS 15          // 15*16 = 240 >= 234
#define GPK 12090        // 155*156/2 packed lower (row 154 = rhs row)
#define PB 11
#define NPAN 14
#define ST 512
#define STR 168          // LDS row stride in floats
#define GT 512           // k_gram threads (8 waves)
#define MAXT 9           // max tiles per wave

#define G_BYTES ((size_t)Bn * GPK * 8)

typedef __attribute__((ext_vector_type(4))) double f64x4;

__device__ __forceinline__ int rb(int i) { return (i * (i + 1)) >> 1; }

// ---------------- k_pre: stream-reduce b_s_ and xm over K -------------------
__global__ __launch_bounds__(1024) void k_pre(
    const float* __restrict__ uv, const float* __restrict__ xm,
    const float* __restrict__ bs, const float* __restrict__ Wp,
    const float* __restrict__ m00, const float* __restrict__ m11,
    const float* __restrict__ m02, const float* __restrict__ m12,
    float* __restrict__ pre)
{
    __shared__ float smL[32][30];
    __shared__ float xsL[32][3];
    const int tid = threadIdx.x;
    const int b = blockIdx.y;
    const int n0 = blockIdx.x * 32;
    const float f0 = m00[b], f1 = m11[b], cx = m02[b], cy = m12[b];

    if (tid < 960) {
        const int ni = tid / 30, c = tid - ni * 30;
        const int nc = min(n0 + ni, Nn - 1);
        float acc = 0.0f;
        const float* bp = bs + ((size_t)(b * Kn) * Nn + nc) * 30 + c;
        #pragma unroll
        for (int k = 0; k < Kn; ++k) acc += bp[(size_t)k * Nn * 30];
        smL[ni][c] = acc;
    } else {
        const int v = tid - 960;
        #pragma unroll
        for (int rep = 0; rep < 2; ++rep) {
            const int w = v + rep * 64;
            if (w < 96) {
                const int ni = w / 3, c = w - ni * 3;
                const int nc = min(n0 + ni, Nn - 1);
                float acc = 0.0f;
                const float* xp = xm + ((size_t)(b * Kn) * Nn + nc) * 3 + c;
                #pragma unroll
                for (int k = 0; k < Kn; ++k) acc += xp[(size_t)k * Nn * 3];
                xsL[ni][c] = acc;
            }
        }
    }
    __syncthreads();

    if (tid < 704) {
        const int ni = tid / 22, e = tid - ni * 22;
        const int n = n0 + ni;
        if (n < Nn) {
            const float u = uv[((size_t)b * Nn + n) * 2 + 0];
            const float v = uv[((size_t)b * Nn + n) * 2 + 1];
            const float w = Wp[(size_t)b * Nn + n];
            const float dxu = cx - u, dyv = cy - v;
            float val;
            if (e < 10)       val = w * (f0 * smL[ni][e] + dxu * smL[ni][20 + e]);
            else if (e < 20)  val = w * (f1 * smL[ni][e] + dyv * smL[ni][e + 10]);
            else if (e == 20) val = w * (-f0 * xsL[ni][0] - dxu * xsL[ni][2]);
            else              val = w * (-f1 * xsL[ni][1] - dyv * xsL[ni][2]);
            pre[((size_t)b * Nn + n) * 22 + e] = val;
        }
    }
}

// ------- k_gram: fp64 MFMA Gram, 8 waves, probed layout (r18 config) --------
__global__ __launch_bounds__(GT, 1) void k_gram(
    const float* __restrict__ uv, const float* __restrict__ xm,
    const float* __restrict__ blend, const float* __restrict__ Wp,
    const float* __restrict__ m00, const float* __restrict__ m11,
    const float* __restrict__ m02, const float* __restrict__ m12,
    const float* __restrict__ pre, double* __restrict__ Gpk)
{
    __shared__ float rowsF[2][2 * NPTS][STR];
    const int tid = threadIdx.x;
    const int b = blockIdx.y;
    const int n0 = blockIdx.x * GCH;
    const int nEnd = min(n0 + GCH, Nn);
    const float f0 = m00[b], f1 = m11[b], cx = m02[b], cy = m12[b];

    const int pt = (tid >> 4) & 15, s = tid & 15;   // builders: tid<256
    const int wave = tid >> 6, lane = tid & 63;

    // ---- probe the f64 MFMA fragment layouts empirically ----
    const f64x4 zz = {0.0, 0.0, 0.0, 0.0};
    const f64x4 pr = __builtin_amdgcn_mfma_f64_16x16x4f64((double)lane, 1.0, zz, 0, 0, 0);
    const f64x4 pc = __builtin_amdgcn_mfma_f64_16x16x4f64(1.0, (double)lane, zz, 0, 0, 0);
    const int v0 = (int)pr[0];
    const bool ac0 = (v0 >= 96) && (v0 <= 156) && (((v0 - 96) & 3) == 0);
    const int arow = ac0 ? (lane & 15) : (lane >> 2);
    const int ak   = ac0 ? (lane >> 4) : (lane & 3);
    const int w0 = (int)pc[0];
    const bool bc0 = (w0 >= 96) && (w0 <= 156) && (((w0 - 96) & 3) == 0);
    const int bcol = bc0 ? (lane & 15) : (lane >> 2);
    const int bk   = bc0 ? (lane >> 4) : (lane & 3);
    int orow[4], ocol[4];
    #pragma unroll
    for (int r2 = 0; r2 < 4; ++r2) {
        const int vr = (int)pr[r2];
        orow[r2] = ac0 ? ((vr - 96) >> 2) : ((vr - 6) >> 4);
        const int wr = (int)pc[r2];
        ocol[r2] = bc0 ? ((wr - 96) >> 2) : ((wr - 6) >> 4);
    }

    // per-wave tile list: builder waves (0-3) 5 tiles, others 9 (guard <55)
    const int t0 = (wave < 4) ? wave * 5 : 20 + (wave - 4) * 9;
    const int cnt = (wave < 4) ? 5 : 9;
    int Ia[MAXT], Ja[MAXT];
    {
        int Iv = 0, Jv = t0;
        while (Jv > Iv) { Jv -= (Iv + 1); ++Iv; }
        #pragma unroll
        for (int t = 0; t < MAXT; ++t) {
            Ia[t] = Iv; Ja[t] = Jv;
            ++Jv;
            if (Jv > Iv) { Jv = 0; ++Iv; }
        }
    }

    f64x4 acc[MAXT];
    #pragma unroll
    for (int t = 0; t < MAXT; ++t) acc[t] = (f64x4){0.0, 0.0, 0.0, 0.0};

    float pf[11];
    const bool isBd = tid < 256;

    auto PF = [&](int rnd) {
        if (!isBd) return;
        const int nc = min(n0 + rnd * NPTS + pt, Nn - 1);
        if (s < 12) {
            const int k0 = 2 * s;
            const float* xa = xm + ((size_t)(b * Kn + k0) * Nn + nc) * 3;
            const float* xb = xm + ((size_t)(b * Kn + k0 + 1) * Nn + nc) * 3;
            pf[0] = xa[0]; pf[1] = xa[1]; pf[2] = xa[2];
            pf[3] = xb[0]; pf[4] = xb[1]; pf[5] = xb[2];
            pf[6] = blend[nc * Kn + k0];
            pf[7] = blend[nc * Kn + k0 + 1];
            pf[8] = uv[((size_t)b * Nn + nc) * 2 + 0];
            pf[9] = uv[((size_t)b * Nn + nc) * 2 + 1];
            pf[10] = Wp[(size_t)b * Nn + nc];
        } else if (s < 15) {
            const int e0 = (s - 12) * 8;
            const float* pp = pre + ((size_t)b * Nn + nc) * 22;
            #pragma unroll
            for (int j = 0; j < 8; ++j) pf[j] = (e0 + j < 22) ? pp[e0 + j] : 0.0f;
        }
    };
    auto WR = [&](int rnd, int bufi) {
        if (!isBd) return;
        const int n = n0 + rnd * NPTS + pt;
        float* rx = &rowsF[bufi][2 * pt][0];
        float* ry = &rowsF[bufi][2 * pt + 1][0];
        if (s < 12) {
            #pragma unroll
            for (int jj = 0; jj < 2; ++jj) {
                float vx[6], vy[6];
                if (n < nEnd) {
                    const float x0 = pf[jj * 3 + 0], x1 = pf[jj * 3 + 1], x2 = pf[jj * 3 + 2];
                    const float dxu = cx - pf[8], dyv = cy - pf[9], w = pf[10];
                    const float wbl = w * pf[6 + jj];
                    vx[0] = w * dxu * x1; vx[1] = w * (f0 * x2 - dxu * x0); vx[2] = -w * f0 * x1;
                    vx[3] = wbl * f0;     vx[4] = 0.0f;                     vx[5] = wbl * dxu;
                    vy[0] = w * (dyv * x1 - f1 * x2); vy[1] = -w * dyv * x0; vy[2] = w * f1 * x0;
                    vy[3] = 0.0f;         vy[4] = wbl * f1;                 vy[5] = wbl * dyv;
                } else {
                    #pragma unroll
                    for (int e = 0; e < 6; ++e) { vx[e] = 0.0f; vy[e] = 0.0f; }
                }
                const int cb = 6 * (2 * s + jj);
                #pragma unroll
                for (int e = 0; e < 6; ++e) {
                    rx[cb + e] = vx[e];
                    ry[cb + e] = vy[e];
                }
            }
        } else if (s < 15) {
            const int e0 = (s - 12) * 8;
            #pragma unroll
            for (int j = 0; j < 8; ++j) {
                const int e = e0 + j;
                if (e < 22) {
                    const float val = (n < nEnd) ? pf[j] : 0.0f;
                    if (e < 10)       rx[144 + e] = val;
                    else if (e < 20)  ry[144 + (e - 10)] = val;
                    else if (e == 20) rx[154] = val;
                    else              ry[154] = val;
                }
            }
        }
    };

    // zero pad cols 155..159
    for (int idx = tid; idx < 320; idx += GT) {
        const int bufi = idx / 160, rem = idx % 160;
        rowsF[bufi][rem / 5][155 + rem % 5] = 0.0f;
    }

    PF(0);
    WR(0, 0);
    PF(1);
    __syncthreads();

    for (int r = 0; r < RNDS; ++r) {
        const int cur = r & 1;
        if (r < RNDS - 1) {
            WR(r + 1, cur ^ 1);
            if (r + 2 < RNDS) PF(r + 2);
        }
        #pragma unroll
        for (int ksl = 0; ksl < 8; ++ksl) {
            const float* rowA = &rowsF[cur][4 * ksl + ak][0];
            const float* rowB = &rowsF[cur][4 * ksl + bk][0];
            #pragma unroll
            for (int t = 0; t < MAXT; ++t) {
                if (t < cnt && t0 + t < 55) {
                    const double av = (double)rowA[16 * Ia[t] + arow];
                    const double bv = (double)rowB[16 * Ja[t] + bcol];
                    acc[t] = __builtin_amdgcn_mfma_f64_16x16x4f64(av, bv, acc[t], 0, 0, 0);
                }
            }
        }
        __syncthreads();
    }

    // write-out via probed output mapping
    double* Gb = Gpk + (size_t)b * GPK;
    #pragma unroll
    for (int t = 0; t < MAXT; ++t) {
        if (t < cnt && t0 + t < 55) {
            #pragma unroll
            for (int rr = 0; rr < 4; ++rr) {
                const int gi = 16 * Ia[t] + orow[rr];
                const int gj = 16 * Ja[t] + ocol[rr];
                if (gi < 155 && gj < 155 && gj <= gi)
                    unsafeAtomicAdd(&Gb[rb(gi) + gj], acc[t][rr]);
            }
        }
    }
}

// ------- k_solve: bordered LDL^T, 2x2-tiled trailing update -----------------
__global__ __launch_bounds__(ST, 2) void k_solve(
    const float* __restrict__ pbeta, const float* __restrict__ vR,
    const double* __restrict__ Gpk, float* __restrict__ out)
{
    __shared__ double tri[12090];     // packed lower 155 rows (row 154 = rhs)
    __shared__ double fd[NPAN][66];   // factored diag blocks
    __shared__ double Pp[144][PB];    // scaled panel rows
    __shared__ double Qq[144][PB];    // raw panel rows
    __shared__ double cv[160];        // final solution x (written in bwd)
    __shared__ double xv[160];        // w = D^-1 L^-1 c, then bwd-updated
    __shared__ double dinv[160];
    const int tid = threadIdx.x;
    const int b = blockIdx.x;
    const double lam2 = 1.0 / 9.0;
    const double* Gb = Gpk + (size_t)b * GPK;

    for (int idx = tid; idx < GPK; idx += ST) tri[idx] = Gb[idx];
    __syncthreads();
    if (tid < 10) {
        const int d = 144 + tid;
        tri[rb(d) + d] += lam2;                                  // Tikhonov
        tri[rb(154) + 144 + tid] += lam2 * (double)pbeta[b * 10 + tid];  // rhs reg
    }
    __syncthreads();

    // ===== bordered factorization: panels over cols 0..153, rows 0..154 =====
    for (int p = 0; p < NPAN; ++p) {
        const int c0 = p * PB, r0 = c0 + PB;
        const int m2 = 155 - r0;   // trailing rows incl. rhs row

        // phase 1: diag block factor, redundant in registers
        double dblk[66], dl[PB];
        #pragma unroll
        for (int r = 0; r < PB; ++r) {
            const int baser = rb(c0 + r) + c0;
            #pragma unroll
            for (int c = 0; c <= r; ++c) dblk[r * (r + 1) / 2 + c] = tri[baser + c];
        }
        #pragma unroll
        for (int j = 0; j < PB; ++j) {
            const double invd = 1.0 / dblk[j * (j + 1) / 2 + j];
            dl[j] = invd;
            #pragma unroll
            for (int r = j + 1; r < PB; ++r) {
                const double mr = dblk[r * (r + 1) / 2 + j] * invd;
                #pragma unroll
                for (int c = j + 1; c <= r; ++c)
                    dblk[r * (r + 1) / 2 + c] -= mr * dblk[c * (c + 1) / 2 + j];
            }
        }
        if (tid == 0) {
            #pragma unroll
            for (int e = 0; e < 66; ++e) fd[p][e] = dblk[e];
            #pragma unroll
            for (int j = 0; j < PB; ++j) dinv[c0 + j] = dl[j];
        }

        // phase 2: panel rows (incl. row 154 = rhs -> fwd substitution free)
        for (int i = r0 + tid; i < 155; i += ST) {
            const int ip = i - r0;
            const int base = rb(i) + c0;
            double a[PB], bbv[PB];
            #pragma unroll
            for (int k = 0; k < PB; ++k) a[k] = tri[base + k];
            #pragma unroll
            for (int t = 0; t < PB; ++t) {
                const double bt = a[t] * dl[t];
                bbv[t] = bt;
                #pragma unroll
                for (int k = t + 1; k < PB; ++k)
                    a[k] -= bt * dblk[k * (k + 1) / 2 + t];
            }
            #pragma unroll
            for (int k = 0; k < PB; ++k) {
                tri[base + k] = a[k]; Pp[ip][k] = bbv[k]; Qq[ip][k] = a[k];
            }
        }
        __syncthreads();

        // phase 3: trailing rank-11 update, 2x2 register tiles
        {
            const int th2 = (m2 + 1) >> 1;            // tile rows
            const int ttot = (th2 * (th2 + 1)) >> 1;  // lower-tri tile count
            for (int e = tid; e < ttot; e += ST) {
                int tr = (int)((sqrtf(8.0f * (float)e + 1.0f) - 1.0f) * 0.5f);
                while ((tr + 1) * (tr + 2) / 2 <= e) ++tr;
                while (tr * (tr + 1) / 2 > e) --tr;
                const int tc = e - ((tr * (tr + 1)) >> 1);
                const int rg0 = 2 * tr, cg0 = 2 * tc;
                const bool r1ok = (rg0 + 1) < m2;
                const bool c1ok = (cg0 + 1) < m2;
                double pa0[PB], pa1[PB], qb0[PB], qb1[PB];
                #pragma unroll
                for (int k = 0; k < PB; ++k) {
                    pa0[k] = Pp[rg0][k];
                    pa1[k] = r1ok ? Pp[rg0 + 1][k] : 0.0;
                    qb0[k] = Qq[cg0][k];
                    qb1[k] = c1ok ? Qq[cg0 + 1][k] : 0.0;
                }
                double s00 = 0.0, s01 = 0.0, s10 = 0.0, s11 = 0.0;
                #pragma unroll
                for (int k = 0; k < PB; ++k) {
                    s00 += pa0[k] * qb0[k];
                    s01 += pa0[k] * qb1[k];
                    s10 += pa1[k] * qb0[k];
                    s11 += pa1[k] * qb1[k];
                }
                // element (0,0): always valid (cg0 <= rg0 since tc <= tr)
                tri[rb(r0 + rg0) + r0 + cg0] -= s00;
                // (0,1): valid iff cg0+1 <= rg0 and c1ok
                if (c1ok && (cg0 + 1) <= rg0)
                    tri[rb(r0 + rg0) + r0 + cg0 + 1] -= s01;
                // (1,0): valid iff r1ok (cg0 <= rg0+1 always)
                if (r1ok)
                    tri[rb(r0 + rg0 + 1) + r0 + cg0] -= s10;
                // (1,1): valid iff r1ok && c1ok (cg0+1 <= rg0+1 always)
                if (r1ok && c1ok)
                    tri[rb(r0 + rg0 + 1) + r0 + cg0 + 1] -= s11;
            }
        }
        __syncthreads();
    }

    // w = D^-1 L^-1 c directly from factored rhs row
    for (int j = tid; j < 154; j += ST) xv[j] = tri[rb(154) + j] * dinv[j];
    __syncthreads();

    // ================= backward substitution =================
    for (int p = NPAN - 1; p >= 0; --p) {
        const int c0 = p * PB;
        double x[PB], dl[PB];
        #pragma unroll
        for (int r = 0; r < PB; ++r) { dl[r] = dinv[c0 + r]; x[r] = xv[c0 + r]; }
        #pragma unroll
        for (int j = PB - 1; j >= 1; --j) {
            #pragma unroll
            for (int i2 = 0; i2 < j; ++i2)
                x[i2] -= dl[i2] * fd[p][j * (j + 1) / 2 + i2] * x[j];
        }
        if (tid == 0) {
            #pragma unroll
            for (int r = 0; r < PB; ++r) cv[c0 + r] = x[r];
        }
        for (int i = tid; i < c0; i += ST) {
            double sum = 0.0;
            #pragma unroll
            for (int jj = 0; jj < PB; ++jj) sum += tri[rb(c0 + jj) + i] * x[jj];
            xv[i] -= dinv[i] * sum;
        }
        __syncthreads();
    }

    // ================= epilogue: Rodrigues + outputs (float32) ==========
    if (tid < Kn) {
        const int k = tid;
        const double rxv = cv[6 * k + 0], ryv = cv[6 * k + 1], rzv = cv[6 * k + 2];
        const double t0 = cv[6 * k + 3], t1 = cv[6 * k + 4], t2 = cv[6 * k + 5];
        const double nrm = sqrt(rxv * rxv + ryv * ryv + rzv * rzv);
        const double th = fmax(nrm, 1e-8);
        const double ax = rxv / th, ay = ryv / th, az = rzv / th;
        const double c = cos(th), sn = sin(th), mc = 1.0 - c;
        double R[3][3];
        R[0][0] = c + mc * ax * ax;        R[0][1] = -sn * az + mc * ax * ay; R[0][2] =  sn * ay + mc * ax * az;
        R[1][0] =  sn * az + mc * ay * ax; R[1][1] = c + mc * ay * ay;        R[1][2] = -sn * ax + mc * ay * az;
        R[2][0] = -sn * ay + mc * az * ax; R[2][1] =  sn * ax + mc * az * ay; R[2][2] = c + mc * az * az;

        const float* VRp = vR + ((size_t)(b * Kn + k)) * 16;
        float* oc = out + ((size_t)(b * Kn + k)) * 16;
        #pragma unroll
        for (int r = 0; r < 3; ++r)
            #pragma unroll
            for (int cc = 0; cc < 4; ++cc) {
                const double val = R[r][0] * (double)VRp[0 * 4 + cc]
                                 + R[r][1] * (double)VRp[1 * 4 + cc]
                                 + R[r][2] * (double)VRp[2 * 4 + cc];
                oc[r * 4 + cc] = (float)val;
            }
        #pragma unroll
        for (int cc = 0; cc < 4; ++cc) oc[12 + cc] = VRp[12 + cc];

        float* ot = out + 24576 + ((size_t)(b * Kn + k)) * 3;
        ot[0] = (float)t0; ot[1] = (float)t1; ot[2] = (float)t2;

        float* orp = out + 29824 + ((size_t)(b * Kn + k)) * 9;
        #pragma unroll
        for (int r = 0; r < 3; ++r)
            #pragma unroll
            for (int cc = 0; cc < 3; ++cc)
                orp[r * 3 + cc] = (float)R[r][cc];
    }
    if (tid >= 32 && tid < 42) {
        out[29184 + b * 10 + (tid - 32)] = (float)cv[144 + (tid - 32)];
    }
}

extern "C" void kernel_launch(void* const* d_in, const int* in_sizes, int n_in,
                              void* d_out, int out_size, void* d_ws, size_t ws_size,
                              hipStream_t stream) {
    const float* uv    = (const float*)d_in[0];
    const float* xm    = (const float*)d_in[1];
    const float* bs    = (const float*)d_in[2];
    const float* blend = (const float*)d_in[3];
    const float* Wp    = (const float*)d_in[4];
    const float* m00   = (const float*)d_in[5];
    const float* m11   = (const float*)d_in[6];
    const float* m02   = (const float*)d_in[7];
    const float* m12   = (const float*)d_in[8];
    const float* pbeta = (const float*)d_in[9];
    const float* vRp   = (const float*)d_in[10];
    float* out = (float*)d_out;
    double* Gpk = (double*)d_ws;
    float* pre = (float*)((char*)d_ws + G_BYTES);

    hipMemsetAsync(d_ws, 0, G_BYTES, stream);

    dim3 gP((Nn + 31) / 32, Bn);
    k_pre<<<gP, 1024, 0, stream>>>(uv, xm, bs, Wp, m00, m11, m02, m12, pre);

    dim3 gG(NBLK, Bn);
    k_gram<<<gG, GT, 0, stream>>>(uv, xm, blend, Wp, m00, m11, m02, m12, pre, Gpk);

    k_solve<<<Bn, ST, 0, stream>>>(pbeta, vRp, Gpk, out);
}

// Round 21
// 228.026 us; speedup vs baseline: 1.1444x; 1.0052x over previous
//
#include <hip/hip_runtime.h>
#include <hip/hip_bf16.h>

#define Bn 64
#define Kn 24
#define Nn 934
#define NBLK 4
#define GCH 234          // points per gram block
#define NPTS 16
#define RNDS 15          // 15*16 = 240 >= 234
#define GPK 12090        // 155*156/2 packed lower (row 154 = rhs row)
#define PB 11
#define NPAN 14
#define ST 512
#define CSTR 36          // col stride in dwords (144B, 16B-aligned)
#define GT 512           // k_gram threads (8 waves)
#define MAXT 9           // max tiles per wave

#define G_BYTES ((size_t)Bn * GPK * 8)

typedef __attribute__((ext_vector_type(4))) double f64x4;

__device__ __forceinline__ int rb(int i) { return (i * (i + 1)) >> 1; }

// ---------------- k_pre: stream-reduce b_s_ and xm over K -------------------
__global__ __launch_bounds__(1024) void k_pre(
    const float* __restrict__ uv, const float* __restrict__ xm,
    const float* __restrict__ bs, const float* __restrict__ Wp,
    const float* __restrict__ m00, const float* __restrict__ m11,
    const float* __restrict__ m02, const float* __restrict__ m12,
    float* __restrict__ pre)
{
    __shared__ float smL[32][30];
    __shared__ float xsL[32][3];
    const int tid = threadIdx.x;
    const int b = blockIdx.y;
    const int n0 = blockIdx.x * 32;
    const float f0 = m00[b], f1 = m11[b], cx = m02[b], cy = m12[b];

    if (tid < 960) {
        const int ni = tid / 30, c = tid - ni * 30;
        const int nc = min(n0 + ni, Nn - 1);
        float acc = 0.0f;
        const float* bp = bs + ((size_t)(b * Kn) * Nn + nc) * 30 + c;
        #pragma unroll
        for (int k = 0; k < Kn; ++k) acc += bp[(size_t)k * Nn * 30];
        smL[ni][c] = acc;
    } else {
        const int v = tid - 960;
        #pragma unroll
        for (int rep = 0; rep < 2; ++rep) {
            const int w = v + rep * 64;
            if (w < 96) {
                const int ni = w / 3, c = w - ni * 3;
                const int nc = min(n0 + ni, Nn - 1);
                float acc = 0.0f;
                const float* xp = xm + ((size_t)(b * Kn) * Nn + nc) * 3 + c;
                #pragma unroll
                for (int k = 0; k < Kn; ++k) acc += xp[(size_t)k * Nn * 3];
                xsL[ni][c] = acc;
            }
        }
    }
    __syncthreads();

    if (tid < 704) {
        const int ni = tid / 22, e = tid - ni * 22;
        const int n = n0 + ni;
        if (n < Nn) {
            const float u = uv[((size_t)b * Nn + n) * 2 + 0];
            const float v = uv[((size_t)b * Nn + n) * 2 + 1];
            const float w = Wp[(size_t)b * Nn + n];
            const float dxu = cx - u, dyv = cy - v;
            float val;
            if (e < 10)       val = w * (f0 * smL[ni][e] + dxu * smL[ni][20 + e]);
            else if (e < 20)  val = w * (f1 * smL[ni][e] + dyv * smL[ni][e + 10]);
            else if (e == 20) val = w * (-f0 * xsL[ni][0] - dxu * xsL[ni][2]);
            else              val = w * (-f1 * xsL[ni][1] - dyv * xsL[ni][2]);
            pre[((size_t)b * Nn + n) * 22 + e] = val;
        }
    }
}

// ------- k_gram: fp64 MFMA Gram, col-major LDS + b128 operand reads ---------
__global__ __launch_bounds__(GT, 1) void k_gram(
    const float* __restrict__ uv, const float* __restrict__ xm,
    const float* __restrict__ blend, const float* __restrict__ Wp,
    const float* __restrict__ m00, const float* __restrict__ m11,
    const float* __restrict__ m02, const float* __restrict__ m12,
    const float* __restrict__ pre, double* __restrict__ Gpk)
{
    __shared__ float rowsT[2][160][CSTR];   // col-major: [buf][col][pointrow]
    const int tid = threadIdx.x;
    const int b = blockIdx.y;
    const int n0 = blockIdx.x * GCH;
    const int nEnd = min(n0 + GCH, Nn);
    const float f0 = m00[b], f1 = m11[b], cx = m02[b], cy = m12[b];

    const int pt = (tid >> 4) & 15, s = tid & 15;   // builders: tid<256
    const int wave = tid >> 6, lane = tid & 63;

    // ---- probe the f64 MFMA fragment layouts empirically ----
    const f64x4 zz = {0.0, 0.0, 0.0, 0.0};
    const f64x4 pr = __builtin_amdgcn_mfma_f64_16x16x4f64((double)lane, 1.0, zz, 0, 0, 0);
    const f64x4 pc = __builtin_amdgcn_mfma_f64_16x16x4f64(1.0, (double)lane, zz, 0, 0, 0);
    const int v0 = (int)pr[0];
    const bool ac0 = (v0 >= 96) && (v0 <= 156) && (((v0 - 96) & 3) == 0);
    const int arow = ac0 ? (lane & 15) : (lane >> 2);
    const int ak   = ac0 ? (lane >> 4) : (lane & 3);
    const int w0 = (int)pc[0];
    const bool bc0 = (w0 >= 96) && (w0 <= 156) && (((w0 - 96) & 3) == 0);
    const int bcol = bc0 ? (lane & 15) : (lane >> 2);
    const int bk   = bc0 ? (lane >> 4) : (lane & 3);
    int orow[4], ocol[4];
    #pragma unroll
    for (int r2 = 0; r2 < 4; ++r2) {
        const int vr = (int)pr[r2];
        orow[r2] = ac0 ? ((vr - 96) >> 2) : ((vr - 6) >> 4);
        const int wr = (int)pc[r2];
        ocol[r2] = bc0 ? ((wr - 96) >> 2) : ((wr - 6) >> 4);
    }

    // per-wave tile list: builder waves (0-3) 5 tiles, others 9 (guard <55)
    const int t0 = (wave < 4) ? wave * 5 : 20 + (wave - 4) * 9;
    const int cnt = (wave < 4) ? 5 : 9;
    int Ia[MAXT], Ja[MAXT];
    {
        int Iv = 0, Jv = t0;
        while (Jv > Iv) { Jv -= (Iv + 1); ++Iv; }
        #pragma unroll
        for (int t = 0; t < MAXT; ++t) {
            Ia[t] = Iv; Ja[t] = Jv;
            ++Jv;
            if (Jv > Iv) { Jv = 0; ++Iv; }
        }
    }

    f64x4 acc[MAXT];
    #pragma unroll
    for (int t = 0; t < MAXT; ++t) acc[t] = (f64x4){0.0, 0.0, 0.0, 0.0};

    float pf[11];
    const bool isBd = tid < 256;

    auto PF = [&](int rnd) {
        if (!isBd) return;
        const int nc = min(n0 + rnd * NPTS + pt, Nn - 1);
        if (s < 12) {
            const int k0 = 2 * s;
            const float* xa = xm + ((size_t)(b * Kn + k0) * Nn + nc) * 3;
            const float* xb = xm + ((size_t)(b * Kn + k0 + 1) * Nn + nc) * 3;
            pf[0] = xa[0]; pf[1] = xa[1]; pf[2] = xa[2];
            pf[3] = xb[0]; pf[4] = xb[1]; pf[5] = xb[2];
            pf[6] = blend[nc * Kn + k0];
            pf[7] = blend[nc * Kn + k0 + 1];
            pf[8] = uv[((size_t)b * Nn + nc) * 2 + 0];
            pf[9] = uv[((size_t)b * Nn + nc) * 2 + 1];
            pf[10] = Wp[(size_t)b * Nn + nc];
        } else if (s < 15) {
            const int e0 = (s - 12) * 8;
            const float* pp = pre + ((size_t)b * Nn + nc) * 22;
            #pragma unroll
            for (int j = 0; j < 8; ++j) pf[j] = (e0 + j < 22) ? pp[e0 + j] : 0.0f;
        }
    };
    auto WR = [&](int rnd, int bufi) {
        if (!isBd) return;
        const int n = n0 + rnd * NPTS + pt;
        const int rx = 2 * pt, ry = 2 * pt + 1;   // point rows (x / y)
        if (s < 12) {
            #pragma unroll
            for (int jj = 0; jj < 2; ++jj) {
                float vx[6], vy[6];
                if (n < nEnd) {
                    const float x0 = pf[jj * 3 + 0], x1 = pf[jj * 3 + 1], x2 = pf[jj * 3 + 2];
                    const float dxu = cx - pf[8], dyv = cy - pf[9], w = pf[10];
                    const float wbl = w * pf[6 + jj];
                    vx[0] = w * dxu * x1; vx[1] = w * (f0 * x2 - dxu * x0); vx[2] = -w * f0 * x1;
                    vx[3] = wbl * f0;     vx[4] = 0.0f;                     vx[5] = wbl * dxu;
                    vy[0] = w * (dyv * x1 - f1 * x2); vy[1] = -w * dyv * x0; vy[2] = w * f1 * x0;
                    vy[3] = 0.0f;         vy[4] = wbl * f1;                 vy[5] = wbl * dyv;
                } else {
                    #pragma unroll
                    for (int e = 0; e < 6; ++e) { vx[e] = 0.0f; vy[e] = 0.0f; }
                }
                const int cb = 6 * (2 * s + jj);
                #pragma unroll
                for (int e = 0; e < 6; ++e) {
                    rowsT[bufi][cb + e][rx] = vx[e];
                    rowsT[bufi][cb + e][ry] = vy[e];
                }
            }
        } else if (s < 15) {
            const int e0 = (s - 12) * 8;
            #pragma unroll
            for (int j = 0; j < 8; ++j) {
                const int e = e0 + j;
                if (e < 22) {
                    const float val = (n < nEnd) ? pf[j] : 0.0f;
                    if (e < 10)       rowsT[bufi][144 + e][rx] = val;
                    else if (e < 20)  rowsT[bufi][144 + (e - 10)][ry] = val;
                    else if (e == 20) rowsT[bufi][154][rx] = val;
                    else              rowsT[bufi][154][ry] = val;
                }
            }
        }
    };

    // zero pad cols 155..159 (all 32 point-rows, both buffers)
    for (int idx = tid; idx < 320; idx += GT) {
        const int bufi = idx / 160, rem = idx % 160;
        rowsT[bufi][155 + rem / 32][rem % 32] = 0.0f;
    }

    PF(0);
    WR(0, 0);
    PF(1);
    __syncthreads();

    for (int r = 0; r < RNDS; ++r) {
        const int cur = r & 1;
        if (r < RNDS - 1) {
            WR(r + 1, cur ^ 1);
            if (r + 2 < RNDS) PF(r + 2);
        }
        #pragma unroll
        for (int t = 0; t < MAXT; ++t) {
            if (t < cnt && t0 + t < 55) {
                const float* colA = &rowsT[cur][16 * Ia[t] + arow][0];
                const float* colB = &rowsT[cur][16 * Ja[t] + bcol][0];
                const float4 a0 = *(const float4*)&colA[8 * ak];
                const float4 a1 = *(const float4*)&colA[8 * ak + 4];
                const float4 b0 = *(const float4*)&colB[8 * bk];
                const float4 b1 = *(const float4*)&colB[8 * bk + 4];
                acc[t] = __builtin_amdgcn_mfma_f64_16x16x4f64((double)a0.x, (double)b0.x, acc[t], 0, 0, 0);
                acc[t] = __builtin_amdgcn_mfma_f64_16x16x4f64((double)a0.y, (double)b0.y, acc[t], 0, 0, 0);
                acc[t] = __builtin_amdgcn_mfma_f64_16x16x4f64((double)a0.z, (double)b0.z, acc[t], 0, 0, 0);
                acc[t] = __builtin_amdgcn_mfma_f64_16x16x4f64((double)a0.w, (double)b0.w, acc[t], 0, 0, 0);
                acc[t] = __builtin_amdgcn_mfma_f64_16x16x4f64((double)a1.x, (double)b1.x, acc[t], 0, 0, 0);
                acc[t] = __builtin_amdgcn_mfma_f64_16x16x4f64((double)a1.y, (double)b1.y, acc[t], 0, 0, 0);
                acc[t] = __builtin_amdgcn_mfma_f64_16x16x4f64((double)a1.z, (double)b1.z, acc[t], 0, 0, 0);
                acc[t] = __builtin_amdgcn_mfma_f64_16x16x4f64((double)a1.w, (double)b1.w, acc[t], 0, 0, 0);
            }
        }
        __syncthreads();
    }

    // write-out via probed output mapping
    double* Gb = Gpk + (size_t)b * GPK;
    #pragma unroll
    for (int t = 0; t < MAXT; ++t) {
        if (t < cnt && t0 + t < 55) {
            #pragma unroll
            for (int rr = 0; rr < 4; ++rr) {
                const int gi = 16 * Ia[t] + orow[rr];
                const int gj = 16 * Ja[t] + ocol[rr];
                if (gi < 155 && gj < 155 && gj <= gi)
                    unsafeAtomicAdd(&Gb[rb(gi) + gj], acc[t][rr]);
            }
        }
    }
}

// ------- k_solve: bordered LDL^T, 2x2-tiled trailing update -----------------
__global__ __launch_bounds__(ST, 2) void k_solve(
    const float* __restrict__ pbeta, const float* __restrict__ vR,
    const double* __restrict__ Gpk, float* __restrict__ out)
{
    __shared__ double tri[12090];     // packed lower 155 rows (row 154 = rhs)
    __shared__ double fd[NPAN][66];   // factored diag blocks
    __shared__ double Pp[144][PB];    // scaled panel rows
    __shared__ double Qq[144][PB];    // raw panel rows
    __shared__ double cv[160];        // final solution x (written in bwd)
    __shared__ double xv[160];        // w = D^-1 L^-1 c, then bwd-updated
    __shared__ double dinv[160];
    const int tid = threadIdx.x;
    const int b = blockIdx.x;
    const double lam2 = 1.0 / 9.0;
    const double* Gb = Gpk + (size_t)b * GPK;

    for (int idx = tid; idx < GPK; idx += ST) tri[idx] = Gb[idx];
    __syncthreads();
    if (tid < 10) {
        const int d = 144 + tid;
        tri[rb(d) + d] += lam2;                                  // Tikhonov
        tri[rb(154) + 144 + tid] += lam2 * (double)pbeta[b * 10 + tid];  // rhs reg
    }
    __syncthreads();

    // ===== bordered factorization: panels over cols 0..153, rows 0..154 =====
    for (int p = 0; p < NPAN; ++p) {
        const int c0 = p * PB, r0 = c0 + PB;
        const int m2 = 155 - r0;   // trailing rows incl. rhs row

        // phase 1: diag block factor, redundant in registers
        double dblk[66], dl[PB];
        #pragma unroll
        for (int r = 0; r < PB; ++r) {
            const int baser = rb(c0 + r) + c0;
            #pragma unroll
            for (int c = 0; c <= r; ++c) dblk[r * (r + 1) / 2 + c] = tri[baser + c];
        }
        #pragma unroll
        for (int j = 0; j < PB; ++j) {
            const double invd = 1.0 / dblk[j * (j + 1) / 2 + j];
            dl[j] = invd;
            #pragma unroll
            for (int r = j + 1; r < PB; ++r) {
                const double mr = dblk[r * (r + 1) / 2 + j] * invd;
                #pragma unroll
                for (int c = j + 1; c <= r; ++c)
                    dblk[r * (r + 1) / 2 + c] -= mr * dblk[c * (c + 1) / 2 + j];
            }
        }
        if (tid == 0) {
            #pragma unroll
            for (int e = 0; e < 66; ++e) fd[p][e] = dblk[e];
            #pragma unroll
            for (int j = 0; j < PB; ++j) dinv[c0 + j] = dl[j];
        }

        // phase 2: panel rows (incl. row 154 = rhs -> fwd substitution free)
        for (int i = r0 + tid; i < 155; i += ST) {
            const int ip = i - r0;
            const int base = rb(i) + c0;
            double a[PB], bbv[PB];
            #pragma unroll
            for (int k = 0; k < PB; ++k) a[k] = tri[base + k];
            #pragma unroll
            for (int t = 0; t < PB; ++t) {
                const double bt = a[t] * dl[t];
                bbv[t] = bt;
                #pragma unroll
                for (int k = t + 1; k < PB; ++k)
                    a[k] -= bt * dblk[k * (k + 1) / 2 + t];
            }
            #pragma unroll
            for (int k = 0; k < PB; ++k) {
                tri[base + k] = a[k]; Pp[ip][k] = bbv[k]; Qq[ip][k] = a[k];
            }
        }
        __syncthreads();

        // phase 3: trailing rank-11 update, 2x2 register tiles
        {
            const int th2 = (m2 + 1) >> 1;            // tile rows
            const int ttot = (th2 * (th2 + 1)) >> 1;  // lower-tri tile count
            for (int e = tid; e < ttot; e += ST) {
                int tr = (int)((sqrtf(8.0f * (float)e + 1.0f) - 1.0f) * 0.5f);
                while ((tr + 1) * (tr + 2) / 2 <= e) ++tr;
                while (tr * (tr + 1) / 2 > e) --tr;
                const int tc = e - ((tr * (tr + 1)) >> 1);
                const int rg0 = 2 * tr, cg0 = 2 * tc;
                const bool r1ok = (rg0 + 1) < m2;
                const bool c1ok = (cg0 + 1) < m2;
                double pa0[PB], pa1[PB], qb0[PB], qb1[PB];
                #pragma unroll
                for (int k = 0; k < PB; ++k) {
                    pa0[k] = Pp[rg0][k];
                    pa1[k] = r1ok ? Pp[rg0 + 1][k] : 0.0;
                    qb0[k] = Qq[cg0][k];
                    qb1[k] = c1ok ? Qq[cg0 + 1][k] : 0.0;
                }
                double s00 = 0.0, s01 = 0.0, s10 = 0.0, s11 = 0.0;
                #pragma unroll
                for (int k = 0; k < PB; ++k) {
                    s00 += pa0[k] * qb0[k];
                    s01 += pa0[k] * qb1[k];
                    s10 += pa1[k] * qb0[k];
                    s11 += pa1[k] * qb1[k];
                }
                tri[rb(r0 + rg0) + r0 + cg0] -= s00;
                if (c1ok && (cg0 + 1) <= rg0)
                    tri[rb(r0 + rg0) + r0 + cg0 + 1] -= s01;
                if (r1ok)
                    tri[rb(r0 + rg0 + 1) + r0 + cg0] -= s10;
                if (r1ok && c1ok)
                    tri[rb(r0 + rg0 + 1) + r0 + cg0 + 1] -= s11;
            }
        }
        __syncthreads();
    }

    // w = D^-1 L^-1 c directly from factored rhs row
    for (int j = tid; j < 154; j += ST) xv[j] = tri[rb(154) + j] * dinv[j];
    __syncthreads();

    // ================= backward substitution =================
    for (int p = NPAN - 1; p >= 0; --p) {
        const int c0 = p * PB;
        double x[PB], dl[PB];
        #pragma unroll
        for (int r = 0; r < PB; ++r) { dl[r] = dinv[c0 + r]; x[r] = xv[c0 + r]; }
        #pragma unroll
        for (int j = PB - 1; j >= 1; --j) {
            #pragma unroll
            for (int i2 = 0; i2 < j; ++i2)
                x[i2] -= dl[i2] * fd[p][j * (j + 1) / 2 + i2] * x[j];
        }
        if (tid == 0) {
            #pragma unroll
            for (int r = 0; r < PB; ++r) cv[c0 + r] = x[r];
        }
        for (int i = tid; i < c0; i += ST) {
            double sum = 0.0;
            #pragma unroll
            for (int jj = 0; jj < PB; ++jj) sum += tri[rb(c0 + jj) + i] * x[jj];
            xv[i] -= dinv[i] * sum;
        }
        __syncthreads();
    }

    // ================= epilogue: Rodrigues + outputs (float32) ==========
    if (tid < Kn) {
        const int k = tid;
        const double rxv = cv[6 * k + 0], ryv = cv[6 * k + 1], rzv = cv[6 * k + 2];
        const double t0 = cv[6 * k + 3], t1 = cv[6 * k + 4], t2 = cv[6 * k + 5];
        const double nrm = sqrt(rxv * rxv + ryv * ryv + rzv * rzv);
        const double th = fmax(nrm, 1e-8);
        const double ax = rxv / th, ay = ryv / th, az = rzv / th;
        const double c = cos(th), sn = sin(th), mc = 1.0 - c;
        double R[3][3];
        R[0][0] = c + mc * ax * ax;        R[0][1] = -sn * az + mc * ax * ay; R[0][2] =  sn * ay + mc * ax * az;
        R[1][0] =  sn * az + mc * ay * ax; R[1][1] = c + mc * ay * ay;        R[1][2] = -sn * ax + mc * ay * az;
        R[2][0] = -sn * ay + mc * az * ax; R[2][1] =  sn * ax + mc * az * ay; R[2][2] = c + mc * az * az;

        const float* VRp = vR + ((size_t)(b * Kn + k)) * 16;
        float* oc = out + ((size_t)(b * Kn + k)) * 16;
        #pragma unroll
        for (int r = 0; r < 3; ++r)
            #pragma unroll
            for (int cc = 0; cc < 4; ++cc) {
                const double val = R[r][0] * (double)VRp[0 * 4 + cc]
                                 + R[r][1] * (double)VRp[1 * 4 + cc]
                                 + R[r][2] * (double)VRp[2 * 4 + cc];
                oc[r * 4 + cc] = (float)val;
            }
        #pragma unroll
        for (int cc = 0; cc < 4; ++cc) oc[12 + cc] = VRp[12 + cc];

        float* ot = out + 24576 + ((size_t)(b * Kn + k)) * 3;
        ot[0] = (float)t0; ot[1] = (float)t1; ot[2] = (float)t2;

        float* orp = out + 29824 + ((size_t)(b * Kn + k)) * 9;
        #pragma unroll
        for (int r = 0; r < 3; ++r)
            #pragma unroll
            for (int cc = 0; cc < 3; ++cc)
                orp[r * 3 + cc] = (float)R[r][cc];
    }
    if (tid >= 32 && tid < 42) {
        out[29184 + b * 10 + (tid - 32)] = (float)cv[144 + (tid - 32)];
    }
}

extern "C" void kernel_launch(void* const* d_in, const int* in_sizes, int n_in,
                              void* d_out, int out_size, void* d_ws, size_t ws_size,
                              hipStream_t stream) {
    const float* uv    = (const float*)d_in[0];
    const float* xm    = (const float*)d_in[1];
    const float* bs    = (const float*)d_in[2];
    const float* blend = (const float*)d_in[3];
    const float* Wp    = (const float*)d_in[4];
    const float* m00   = (const float*)d_in[5];
    const float* m11   = (const float*)d_in[6];
    const float* m02   = (const float*)d_in[7];
    const float* m12   = (const float*)d_in[8];
    const float* pbeta = (const float*)d_in[9];
    const float* vRp   = (const float*)d_in[10];
    float* out = (float*)d_out;
    double* Gpk = (double*)d_ws;
    float* pre = (float*)((char*)d_ws + G_BYTES);

    hipMemsetAsync(d_ws, 0, G_BYTES, stream);

    dim3 gP((Nn + 31) / 32, Bn);
    k_pre<<<gP, 1024, 0, stream>>>(uv, xm, bs, Wp, m00, m11, m02, m12, pre);

    dim3 gG(NBLK, Bn);
    k_gram<<<gG, GT, 0, stream>>>(uv, xm, blend, Wp, m00, m11, m02, m12, pre, Gpk);

    k_solve<<<Bn, ST, 0, stream>>>(pbeta, vRp, Gpk, out);
}